// Round 5
// baseline (8798.628 us; speedup 1.0000x reference)
//
#include <hip/hip_runtime.h>

typedef unsigned short u16;
typedef unsigned int u32;
typedef __bf16 bf16x8 __attribute__((ext_vector_type(8)));
typedef float f32x4 __attribute__((ext_vector_type(4)));
typedef float f32x16 __attribute__((ext_vector_type(16)));
typedef u16 u16x4 __attribute__((ext_vector_type(4)));
typedef u16 u16x8 __attribute__((ext_vector_type(8)));

// Problem constants: B=256, T=512, H=1024
#define HDIM 1024
#define BATCH 256
#define TSTEPS 512
#define BT (BATCH * TSTEPS)   // 131072 rows of x
#define HB_ELEMS (BATCH * HDIM)  // 262144

// ---------- bf16 helpers (RNE, bit-level) ----------
__device__ __forceinline__ u16 f2bf(float f) {
  union { float f; u32 u; } v; v.f = f;
  u32 r = v.u + 0x7FFFu + ((v.u >> 16) & 1u);
  return (u16)(r >> 16);
}
__device__ __forceinline__ float bf2f(u16 u) {
  union { u32 u; float f; } v; v.u = ((u32)u) << 16;
  return v.f;
}

// ---------- async global->LDS, 16B per lane ----------
__device__ __forceinline__ void gload_lds16(const void* g, void* l) {
  __builtin_amdgcn_global_load_lds(
      (const __attribute__((address_space(1))) unsigned int*)g,
      (__attribute__((address_space(3))) unsigned int*)l, 16, 0, 0);
}

// =====================================================================
// Kernel 1: pack weights to bf16 (Wcat=[Wz;Wh], Ucat=[Uz;Uh], N x K),
// init h (fp32 + bf16), zero the group-barrier counters.
// =====================================================================
__global__ __launch_bounds__(256) void pack_kernel(
    const float* __restrict__ Wz, const float* __restrict__ Uz,
    const float* __restrict__ Wh, const float* __restrict__ Uh,
    const float* __restrict__ ht,
    u16* __restrict__ Wcat, u16* __restrict__ Ucat,
    float* __restrict__ hf0, u16* __restrict__ hb0,
    u32* __restrict__ cnt)
{
  if (blockIdx.x == 0 && threadIdx.x < 16) cnt[threadIdx.x] = 0;
  const long M = 1L << 20;  // 1024*1024
  long e = ((long)blockIdx.x * 256 + threadIdx.x) * 4;
  const float* src;
  u16* dst;
  if (e < M)            { src = Wz + e;        dst = Wcat + e; }
  else if (e < 2 * M)   { src = Wh + (e - M);  dst = Wcat + e; }
  else if (e < 3 * M)   { src = Uz + (e - 2*M); dst = Ucat + (e - 2*M); }
  else if (e < 4 * M)   { src = Uh + (e - 3*M); dst = Ucat + (e - 2*M); }
  else {
    long j = e - 4 * M;  // [0, 256*1024)
    float4 v = *(const float4*)(ht + j);
    *(float4*)(hf0 + j) = v;
    u16x4 o = { f2bf(v.x), f2bf(v.y), f2bf(v.z), f2bf(v.w) };
    *(u16x4*)(hb0 + j) = o;
    return;
  }
  float4 v = *(const float4*)src;
  u16x4 o = { f2bf(v.x), f2bf(v.y), f2bf(v.z), f2bf(v.w) };
  *(u16x4*)dst = o;
}

// =====================================================================
// Kernel 2: phase-1 GEMM  xzh[t][b][n] = sum_k x[b][t][k] * Wcat[n][k]
// 128x128 tile, BK=64, B via global_load_lds, A reg-staged fp32->bf16.
// =====================================================================
__global__ __launch_bounds__(256) void gemm_xw(
    const float* __restrict__ x, const u16* __restrict__ Wcat,
    u16* __restrict__ xzh)
{
  __shared__ u16 As[128 * 64];  // 16KB [row][k]
  __shared__ u16 Bs[128 * 64];  // 16KB [n][k]

  const int NWG = (BT / 128) * (2048 / 128);  // 16384
  int bid = blockIdx.x;
  int swz = (bid & 7) * (NWG / 8) + (bid >> 3);  // XCD-contiguous chunks
  int tm = swz >> 4;   // m-tile [0,1024)
  int tn = swz & 15;   // n-tile [0,16)
  long m0 = (long)tm * 128;
  int n0 = tn * 128;

  int tid = threadIdx.x;
  int w = tid >> 6, l = tid & 63;
  int wr = (w >> 1) * 64;
  int wc = (w & 1) * 64;

  f32x4 acc[4][4] = {};

  const int arow = tid >> 3;
  const int acol = (tid & 7) * 8;
  const int brow = l >> 3;
  const int bcol = (l & 7) * 8;

  for (int kc = 0; kc < 16; ++kc) {
    int k0 = kc * 64;
#pragma unroll
    for (int j = 0; j < 4; ++j) {
      int r = (w * 4 + j) * 8 + brow;
      gload_lds16(Wcat + (((long)(n0 + r)) << 10) + k0 + bcol,
                  &Bs[(w * 4 + j) * 512]);
    }
    float4 av[4][2];
#pragma unroll
    for (int s = 0; s < 4; ++s) {
      const float* src = x + ((m0 + arow + s * 32) << 10) + k0 + acol;
      av[s][0] = *(const float4*)src;
      av[s][1] = *(const float4*)(src + 4);
    }
#pragma unroll
    for (int s = 0; s < 4; ++s) {
      u16x8 o = { f2bf(av[s][0].x), f2bf(av[s][0].y), f2bf(av[s][0].z), f2bf(av[s][0].w),
                  f2bf(av[s][1].x), f2bf(av[s][1].y), f2bf(av[s][1].z), f2bf(av[s][1].w) };
      *(u16x8*)(As + tid * 8 + s * 2048) = o;
    }
    __syncthreads();
#pragma unroll
    for (int kk = 0; kk < 2; ++kk) {
      int kb = kk * 32 + (l >> 4) * 8;
      int rr = l & 15;
      bf16x8 af[4], bfr[4];
#pragma unroll
      for (int i = 0; i < 4; ++i)
        af[i] = *(const bf16x8*)(As + (wr + i * 16 + rr) * 64 + kb);
#pragma unroll
      for (int j = 0; j < 4; ++j)
        bfr[j] = *(const bf16x8*)(Bs + (wc + j * 16 + rr) * 64 + kb);
#pragma unroll
      for (int i = 0; i < 4; ++i)
#pragma unroll
        for (int j = 0; j < 4; ++j)
          acc[i][j] = __builtin_amdgcn_mfma_f32_16x16x32_bf16(af[i], bfr[j], acc[i][j], 0, 0, 0);
    }
    __syncthreads();
  }

  int rq = (l >> 4) * 4;
  int rc = l & 15;
#pragma unroll
  for (int i = 0; i < 4; ++i) {
#pragma unroll
    for (int r = 0; r < 4; ++r) {
      long m = m0 + wr + i * 16 + rq + r;
      int b = (int)(m >> 9);
      int t = (int)(m & 511);
      u16* dst = xzh + (((long)t * 256 + b) << 11);
#pragma unroll
      for (int j = 0; j < 4; ++j)
        dst[n0 + wc + j * 16 + rc] = f2bf(acc[i][j][r]);
    }
  }
}

// =====================================================================
// Kernel 3: PERSISTENT GRU scan. 256 blocks (1/CU, forced by 152KB LDS),
// 256 threads. Block (g=bid&7, j=bid>>3): b-rows [32g,32g+32), o-cols
// [32j,32j+32). U rows live in LDS for all 512 steps (128KB, XOR-swizzled
// byte^=((row&7)<<4) — both-sides-consistent). 4 waves = 4 K-quarters,
// both gates per wave (mfma 32x32x16 bf16), cross-wave K-reduce via LDS.
// Cross-block sync: per-group monotonic counter (release add / acquire spin)
// — only the 32 blocks sharing a b-group depend on each other.
// =====================================================================
__global__ __launch_bounds__(256) void gru_scan(
    const u16* __restrict__ Ucat, const u16* __restrict__ xzh,
    u16* __restrict__ hb, float* __restrict__ hf,
    u32* __restrict__ cnt, float* __restrict__ outp)
{
  __shared__ u16 BL[2][32][1024];    // 128KB: [gate][o-col][k], swizzled
  __shared__ float red[3][2][1024];  // 24KB: [srcwave-1][gate][q*256 + l*4 + e]

  int bid = blockIdx.x;
  int g = bid & 7;        // b-group, XCD-affine under round-robin dispatch
  int j = bid >> 3;       // o-tile
  int b0 = g * 32;
  int o0 = j * 32;
  int tid = threadIdx.x;
  int w = tid >> 6;       // wave id == K-quarter
  int l = tid & 63;
  int hi = l >> 5;
  int col = l & 31;
  const int colx = (l & 7) << 4;  // swizzle term ((col&7)<<4)

  // ---- one-time: stage U (both gates) into LDS, swizzled ----
#pragma unroll 1
  for (int gate = 0; gate < 2; ++gate) {
    const u16* src = Ucat + (((long)gate << 20) + ((long)o0 << 10));
    char* dstbase = (char*)&BL[gate][0][0];
#pragma unroll
    for (int i = 0; i < 16; ++i) {
      int c = i * 256 + tid;          // 16B chunk id, 4096 per gate
      int row = c >> 7;               // 0..31
      int inner = (c & 127) << 4;     // byte offset within row
      u16x8 v = *(const u16x8*)(src + row * 1024 + (inner >> 1));
      *(u16x8*)(dstbase + row * 2048 + (inner ^ ((row & 7) << 4))) = v;
    }
  }
  __syncthreads();

  const char* bz_base = (const char*)&BL[0][0][0] + col * 2048;
  const char* bh_base = (const char*)&BL[1][0][0] + col * 2048;
  const int kbase = (w << 9) + (hi << 4);  // byte: q*512 + hi*16

#pragma unroll 1
  for (int t = 0; t < TSTEPS; ++t) {
    int cur = t & 1;
    const u16* hbC = hb + cur * HB_ELEMS;
    const float* hfC = hf + cur * HB_ELEMS;
    u16* hbN = hb + (cur ^ 1) * HB_ELEMS;
    float* hfN = hf + (cur ^ 1) * HB_ELEMS;
    const u16* xt = xzh + (long)t * (BATCH * 2048);

    // ---- group barrier: wait for all 32 blocks of group g to finish t-1 ----
    if (t > 0) {
      if (tid == 0) {
        u32 target = (u32)(32 * t);
        while (__hip_atomic_load(cnt + g, __ATOMIC_ACQUIRE,
                                 __HIP_MEMORY_SCOPE_AGENT) < target) {
          __builtin_amdgcn_s_sleep(1);
        }
      }
      __syncthreads();
    }

    // ---- A loads: this wave's K-quarter of h (16 x 16B per lane) ----
    bf16x8 a[16];
    const u16* hrow = hbC + ((long)(b0 + col) << 10) + (w << 8) + (hi << 3);
#pragma unroll
    for (int ks = 0; ks < 16; ++ks)
      a[ks] = *(const bf16x8*)(hrow + ks * 16);

    // ---- wave0: issue epilogue loads early (hide HBM latency of xzh) ----
    u16 xzv[16], xhv[16];
    float holdv[16];
    if (w == 0) {
#pragma unroll
      for (int r = 0; r < 16; ++r) {
        int row = (r & 3) + ((r >> 2) << 3) + (hi << 2);
        long bq = b0 + row;
        xzv[r] = xt[(bq << 11) + o0 + col];
        xhv[r] = xt[(bq << 11) + 1024 + o0 + col];
        holdv[r] = hfC[(bq << 10) + o0 + col];
      }
    }

    // ---- MFMA: 16 K-slices x 2 gates ----
    f32x16 accZ = {};
    f32x16 accH = {};
#pragma unroll
    for (int ks = 0; ks < 16; ++ks) {
      int koff = (kbase + ks * 32) ^ colx;
      bf16x8 bz = *(const bf16x8*)(bz_base + koff);
      bf16x8 bh = *(const bf16x8*)(bh_base + koff);
      accZ = __builtin_amdgcn_mfma_f32_32x32x16_bf16(a[ks], bz, accZ, 0, 0, 0);
      accH = __builtin_amdgcn_mfma_f32_32x32x16_bf16(a[ks], bh, accH, 0, 0, 0);
    }

    // ---- cross-wave K reduction through LDS ----
    if (w != 0) {
      float* rb = &red[w - 1][0][0];
#pragma unroll
      for (int q = 0; q < 4; ++q) {
        f32x4 vz = { accZ[q*4+0], accZ[q*4+1], accZ[q*4+2], accZ[q*4+3] };
        f32x4 vh = { accH[q*4+0], accH[q*4+1], accH[q*4+2], accH[q*4+3] };
        *(f32x4*)(rb + q * 256 + l * 4) = vz;
        *(f32x4*)(rb + 1024 + q * 256 + l * 4) = vh;
      }
    }
    __syncthreads();

    if (w == 0) {
#pragma unroll
      for (int i = 0; i < 3; ++i) {
        const float* rb = &red[i][0][0];
#pragma unroll
        for (int q = 0; q < 4; ++q) {
          f32x4 vz = *(const f32x4*)(rb + q * 256 + l * 4);
          f32x4 vh = *(const f32x4*)(rb + 1024 + q * 256 + l * 4);
          accZ[q*4+0] += vz[0]; accZ[q*4+1] += vz[1];
          accZ[q*4+2] += vz[2]; accZ[q*4+3] += vz[3];
          accH[q*4+0] += vh[0]; accH[q*4+1] += vh[1];
          accH[q*4+2] += vh[2]; accH[q*4+3] += vh[3];
        }
      }
      // ---- epilogue (fp32): z, tanh, convex combine, store h' ----
      bool last = (t == TSTEPS - 1);
#pragma unroll
      for (int r = 0; r < 16; ++r) {
        int row = (r & 3) + ((r >> 2) << 3) + (hi << 2);
        long bq = b0 + row;
        float zp = accZ[r] + bf2f(xzv[r]);
        float hp = accH[r] + bf2f(xhv[r]);
        float z = 1.f / (1.f + __expf(-zp));
        float th = tanhf(hp);
        float hnew = z * holdv[r] + (1.f - z) * th;
        if (last) {
          outp[(bq << 10) + o0 + col] = hnew;
          outp[(long)HB_ELEMS + (bq << 10) + o0 + col] = hnew;
        } else {
          hfN[(bq << 10) + o0 + col] = hnew;
          hbN[(bq << 10) + o0 + col] = f2bf(hnew);
        }
      }
      // ---- signal: release-add (drains this wave's stores first) ----
      if (!last && tid == 0) {
        __hip_atomic_fetch_add(cnt + g, 1u, __ATOMIC_RELEASE,
                               __HIP_MEMORY_SCOPE_AGENT);
      }
    }
  }
}

// =====================================================================
extern "C" void kernel_launch(void* const* d_in, const int* in_sizes, int n_in,
                              void* d_out, int out_size, void* d_ws, size_t ws_size,
                              hipStream_t stream)
{
  const float* x  = (const float*)d_in[0];
  const float* ht = (const float*)d_in[1];
  const float* Wz = (const float*)d_in[2];
  const float* Uz = (const float*)d_in[3];
  // d_in[4]=Wr, d_in[5]=Ur are dead in the reference
  const float* Wh = (const float*)d_in[6];
  const float* Uh = (const float*)d_in[7];

  char* ws = (char*)d_ws;
  // layout: xzh 512MB | Wcat 4MB | Ucat 4MB | hf 2MB | hb 1MB | cnt 64B
  u16*   xzh  = (u16*)ws;
  u16*   Wcat = (u16*)(ws + 536870912L);
  u16*   Ucat = (u16*)(ws + 541065216L);
  float* hf   = (float*)(ws + 545259520L);
  u16*   hb   = (u16*)(ws + 547356672L);
  u32*   cnt  = (u32*)(ws + 548405248L);

  pack_kernel<<<4352, 256, 0, stream>>>(Wz, Uz, Wh, Uh, ht, Wcat, Ucat, hf, hb, cnt);
  gemm_xw<<<16384, 256, 0, stream>>>(x, Wcat, xzh);
  gru_scan<<<256, 256, 0, stream>>>(Ucat, xzh, hb, hf, cnt, (float*)d_out);
}